// Round 19
// baseline (240.433 us; speedup 1.0000x reference)
//
#include <hip/hip_runtime.h>
#include <math.h>

#define BATCH 8
#define SEQ 1024
#define D_MODEL 512
#define D_INNER 1024
#define D_STATE 16
#define DT_RANK 32
#define NROWS (BATCH * SEQ)   // 8192
#define CH 64                 // chunks per sequence
#define CL 16                 // chunk length
#define USLAB 8388608l        // 8192*1024 elems (one dir slab)

typedef short short8 __attribute__((ext_vector_type(8)));
typedef float f32x4 __attribute__((ext_vector_type(4)));

__device__ __forceinline__ float sigmoidf_(float x) { return 1.f / (1.f + __expf(-x)); }

__device__ __forceinline__ float softplus_(float v) {
  return (v > 20.f) ? v : __logf(1.f + __expf(v));
}

__device__ __forceinline__ ushort f2b(float f) {  // fp32 -> bf16 RNE
  uint u = __float_as_uint(f);
  return (ushort)((u + 0x7FFFu + ((u >> 16) & 1u)) >> 16);
}
__device__ __forceinline__ float b2f(ushort u) {
  return __uint_as_float(((uint)u) << 16);
}

__device__ __forceinline__ void gload16(const ushort* g, const ushort* l) {
  __builtin_amdgcn_global_load_lds(
      (const __attribute__((address_space(1))) void*)g,
      (__attribute__((address_space(3))) void*)l, 16, 0, 0);
}

__device__ __forceinline__ int revrow(int m) {
  return (m & ~1023) | (1023 - (m & 1023));
}

#define VMCNT0 asm volatile("s_waitcnt vmcnt(0)" ::: "memory")
#define VMCNT2 asm volatile("s_waitcnt vmcnt(2)" ::: "memory")
#define VMCNT4 asm volatile("s_waitcnt vmcnt(4)" ::: "memory")

// -------- bf16 MFMA GEMM: 3-buffer counted-vmcnt, single barrier/K-tile ----
// EPI: 0 = fp32 store (revC/accumC)
//      1 = softplus(v+bias[n]) -> bf16 (LDS-transposed, pad-80 scratch)
//      2 = in_proj split: n -> {dir, u|z}; bwd rows reversed; z gets silu
//      4 = plain bf16 scattered
template<int BM, int BN, int RW, int CW, int EPI, int DUALK, int MDIAG>
__global__ __launch_bounds__(256) void gemm_bf16(
    const ushort* __restrict__ A, int lda, const ushort* __restrict__ A2,
    const ushort* __restrict__ B, int ldb, const ushort* __restrict__ B2,
    float* __restrict__ Cf, ushort* __restrict__ Cb, ushort* __restrict__ Cb2,
    int ldc, int K, const float* __restrict__ bias, const float* __restrict__ bias2,
    int b_stride, int revC, int accumC)
{
  constexpr int MI = BM / RW / 16;
  constexpr int NJ = BN / CW / 16;
  constexpr int LPS = BM / 64 + BN / 64;   // loads per stage per thread
  __shared__ ushort As[3][BM * 32];
  __shared__ ushort Bs[3][BN * 32];
  const int tid = threadIdx.x;
  const int w = tid >> 6, lane = tid & 63;

  const int nwg = gridDim.x * gridDim.y;
  int bid = blockIdx.y * gridDim.x + blockIdx.x;
  int wgid = (bid & 7) * (nwg >> 3) + (bid >> 3);
  const int bm = (wgid / gridDim.x) * BM;
  const int bn = (wgid % gridDim.x) * BN;

  if (MDIAG) {
    int mdir = (bm >= NROWS) ? 1 : 0;
    B += mdir * b_stride;
    if (mdir) bias = bias2;
  }

  const int rw0 = (w / CW) * (MI * 16);
  const int cw0 = (w % CW) * (NJ * 16);
  const int srow = w * 16 + (lane >> 2);
  const int scol = (((lane & 3) ^ ((lane >> 3) & 3)) << 3);
  const int rchunk = (((lane >> 4) ^ (((lane & 15) >> 1) & 3)) << 3);

  f32x4 acc[MI][NJ] = {};

  auto stage = [&](int buf, int k0) {
    const ushort* Ap = A;
    const ushort* Bp = B;
    int kc = k0;
    bool hi = false;
    if (DUALK && k0 >= (K >> 1)) { Ap = A2; Bp = B2; kc = k0 - (K >> 1); hi = true; }
#pragma unroll
    for (int it = 0; it < BM / 64; ++it) {
      int gm = bm + it * 64 + srow;
      int arow = (DUALK && hi) ? revrow(gm) : gm;
      gload16(Ap + (long)arow * lda + kc + scol, &As[buf][(it * 64 + w * 16) * 32]);
    }
#pragma unroll
    for (int it = 0; it < BN / 64; ++it) {
      int gn = bn + it * 64 + srow;
      gload16(Bp + (long)gn * ldb + kc + scol, &Bs[buf][(it * 64 + w * 16) * 32]);
    }
  };

  const int NT = K >> 5;
  stage(0, 0);
  if (NT > 1) {
    stage(1, 32);
    if constexpr (LPS == 2) VMCNT2; else VMCNT4;
  } else {
    VMCNT0;
  }
  __builtin_amdgcn_s_barrier();

  int buf = 0;
  for (int t = 0; t < NT; ++t) {
    short8 a[MI], b[NJ];
#pragma unroll
    for (int i = 0; i < MI; ++i)
      a[i] = *(const short8*)&As[buf][(rw0 + i * 16 + (lane & 15)) * 32 + rchunk];
#pragma unroll
    for (int j = 0; j < NJ; ++j)
      b[j] = *(const short8*)&Bs[buf][(cw0 + j * 16 + (lane & 15)) * 32 + rchunk];
    int sbuf = (buf >= 1) ? buf - 1 : buf + 2;
    if (t + 2 < NT) {
      stage(sbuf, (t + 2) << 5);
      if constexpr (LPS == 2) VMCNT2; else VMCNT4;
    } else if (t + 1 < NT) {
      VMCNT0;
    }
    __builtin_amdgcn_s_barrier();
    __builtin_amdgcn_s_setprio(1);
#pragma unroll
    for (int i = 0; i < MI; ++i)
#pragma unroll
      for (int j = 0; j < NJ; ++j)
        acc[i][j] = __builtin_amdgcn_mfma_f32_16x16x32_bf16(a[i], b[j], acc[i][j], 0, 0, 0);
    __builtin_amdgcn_s_setprio(0);
    buf = (buf == 2) ? 0 : buf + 1;
  }
  __builtin_amdgcn_s_barrier();   // all ds_reads done before scr overlay

  if (EPI == 1) {
    // LDS-transposed bf16 stores; pad-80 rows: concurrent rows hit disjoint
    // 8-bank ranges (write conflict-free, reads <=2-way)
    ushort* scr = &As[0][0] + w * 1280;
#pragma unroll
    for (int i = 0; i < MI; ++i) {
#pragma unroll
      for (int r = 0; r < 4; ++r)
#pragma unroll
        for (int j = 0; j < NJ; ++j) {
          int n = bn + cw0 + j * 16 + (lane & 15);
          float v = softplus_(acc[i][j][r] + bias[n]);
          scr[((lane >> 4) * 4 + r) * 80 + j * 16 + (lane & 15)] = f2b(v);
        }
#pragma unroll
      for (int q = 0; q < 2; ++q) {
        int r16 = (lane >> 3) + q * 8;
        short8 pk = *(const short8*)&scr[r16 * 80 + (lane & 7) * 8];
        int m = bm + rw0 + i * 16 + r16;
        *(short8*)&Cb[(long)m * ldc + bn + cw0 + (lane & 7) * 8] = pk;
      }
    }
  } else if (EPI == 2) {
    const int bdir = bn >> 11;
    const int bz = ((bn & 2047) >= 1024);
    const int bncol = bn & 1023;
    ushort* Cp = (bz ? Cb2 : Cb) + (long)bdir * USLAB;
    ushort* scr = &As[0][0] + w * 1280;
#pragma unroll
    for (int i = 0; i < MI; ++i) {
#pragma unroll
      for (int r = 0; r < 4; ++r)
#pragma unroll
        for (int j = 0; j < NJ; ++j) {
          float v = acc[i][j][r];
          if (bz) v = v * sigmoidf_(v);
          scr[((lane >> 4) * 4 + r) * 80 + j * 16 + (lane & 15)] = f2b(v);
        }
#pragma unroll
      for (int q = 0; q < 2; ++q) {
        int r16 = (lane >> 3) + q * 8;
        short8 pk = *(const short8*)&scr[r16 * 80 + (lane & 7) * 8];
        int m = bm + rw0 + i * 16 + r16;
        int row = bdir ? revrow(m) : m;
        *(short8*)&Cp[(long)row * 1024 + bncol + cw0 + (lane & 7) * 8] = pk;
      }
    }
  } else {
#pragma unroll
    for (int i = 0; i < MI; ++i)
#pragma unroll
      for (int r = 0; r < 4; ++r) {
        int m = bm + rw0 + i * 16 + (lane >> 4) * 4 + r;
        int crow = revC ? revrow(m) : m;
#pragma unroll
        for (int j = 0; j < NJ; ++j) {
          int n = bn + cw0 + j * 16 + (lane & 15);
          float v = acc[i][j][r];
          if (EPI == 0) {
            float* p = Cf + (long)crow * ldc + n;
            if (accumC) *p += v; else *p = v;
          } else {  // EPI == 4
            Cb[(long)crow * ldc + n] = f2b(v);
          }
        }
      }
  }
}

// ---------------- fused fp32->bf16 converter (x + 8 weight tensors) --------
struct Seg { const float4* s; ushort4* d; int n4; int bstart; };
struct ConvArgs { Seg seg[9]; };

__global__ __launch_bounds__(256) void convert_all(ConvArgs a)
{
  int blk = blockIdx.x;
  int i = 0;
#pragma unroll
  for (int k = 1; k < 9; ++k) if (blk >= a.seg[k].bstart) i = k;
  int idx = (blk - a.seg[i].bstart) * 256 + threadIdx.x;
  if (idx >= a.seg[i].n4) return;
  float4 v = a.seg[i].s[idx];
  ushort4 o;
  o.x = f2b(v.x); o.y = f2b(v.y); o.z = f2b(v.z); o.w = f2b(v.w);
  a.seg[i].d[idx] = o;
}

// ------------- conv1d(k=4) + bias + silu, both dirs (4 d/thread) -----------
__global__ __launch_bounds__(256) void conv_silu(
    const ushort* __restrict__ u_bf,
    const float* __restrict__ cw_f, const float* __restrict__ cw_b,
    const float* __restrict__ cb_f, const float* __restrict__ cb_b,
    ushort* __restrict__ uc_bf)
{
  long i = (long)blockIdx.x * 256 + threadIdx.x;
  int dir = (int)(i >> 21);
  int r = (int)(i >> 8) & 8191;
  int d0 = ((int)i & 255) << 2;
  int t = r & (SEQ - 1);
  const float* cw = dir ? cw_b : cw_f;
  const float* cb = dir ? cb_b : cb_f;
  const ushort* p = u_bf + dir * USLAB + (long)r * D_INNER + d0;
  ushort4 u0 = *(const ushort4*)p;
  ushort4 u1 = (t >= 1) ? *(const ushort4*)(p - 1024) : ushort4{0, 0, 0, 0};
  ushort4 u2 = (t >= 2) ? *(const ushort4*)(p - 2048) : ushort4{0, 0, 0, 0};
  ushort4 u3 = (t >= 3) ? *(const ushort4*)(p - 3072) : ushort4{0, 0, 0, 0};
  float4 bb = *(const float4*)(cb + d0);
  float ub0[4] = {b2f(u0.x), b2f(u0.y), b2f(u0.z), b2f(u0.w)};
  float ub1[4] = {b2f(u1.x), b2f(u1.y), b2f(u1.z), b2f(u1.w)};
  float ub2[4] = {b2f(u2.x), b2f(u2.y), b2f(u2.z), b2f(u2.w)};
  float ub3[4] = {b2f(u3.x), b2f(u3.y), b2f(u3.z), b2f(u3.w)};
  float bbv[4] = {bb.x, bb.y, bb.z, bb.w};
  ushort ov[4];
#pragma unroll
  for (int j = 0; j < 4; ++j) {
    float4 wj = *(const float4*)(cw + (d0 + j) * 4);
    float acc = bbv[j];
    acc = fmaf(wj.w, ub0[j], acc);
    acc = fmaf(wj.z, ub1[j], acc);
    acc = fmaf(wj.y, ub2[j], acc);
    acc = fmaf(wj.x, ub3[j], acc);
    ov[j] = f2b(acc * sigmoidf_(acc));
  }
  ushort4 o;
  o.x = ov[0]; o.y = ov[1]; o.z = ov[2]; o.w = ov[3];
  *(ushort4*)(uc_bf + dir * USLAB + (long)r * D_INNER + d0) = o;
}

// Decay powers E^(s+1), s=0..15, from E = exp(-dt).
#define EP_FAST(dt, Ep)                                        \
  {                                                            \
    float E1 = __expf(-(dt));                                  \
    float E2 = E1 * E1, E4 = E2 * E2, E8 = E4 * E4;            \
    Ep[0] = E1;  Ep[1] = E2;      Ep[2] = E2 * E1;             \
    Ep[3] = E4;  Ep[4] = E4 * E1; Ep[5] = E4 * E2;             \
    Ep[6] = E4 * Ep[2]; Ep[7] = E8;  Ep[8] = E8 * E1;          \
    Ep[9] = E8 * E2; Ep[10] = E8 * Ep[2]; Ep[11] = E8 * E4;    \
    Ep[12] = E8 * Ep[4]; Ep[13] = E8 * Ep[5];                  \
    Ep[14] = E8 * Ep[6]; Ep[15] = E8 * E8;                     \
  }

__device__ __forceinline__ bool a_is_arange(const float* Ar) {
  bool ok = true;
#pragma unroll
  for (int s = 0; s < D_STATE; ++s)
    ok = ok && (fabsf(Ar[s] + (float)(s + 1)) <= 1e-3f * (float)(s + 1));
  return ok;
}

// ---------------- chunked selective scan (both dirs in one grid) -----------
__global__ __launch_bounds__(256) void scan_partA(
    const ushort* __restrict__ delta_bf,
    const ushort* __restrict__ ucv_bf,
    const ushort* __restrict__ dblb,
    const float* __restrict__ A_log_f, const float* __restrict__ A_log_b,
    ushort* __restrict__ hend,
    float* __restrict__ dtsum_buf)
{
  __shared__ float bc[CL][16];
  long idx = (long)blockIdx.x * 256 + threadIdx.x;
  int d = (int)idx & 1023;
  int c = ((int)idx >> 10) & (CH - 1);
  int b = ((int)idx >> 16) & 7;
  int dir = (int)(idx >> 19);
  const long r0 = (long)b * SEQ + c * CL;
  const ushort* dblp = dblb + (long)dir * NROWS * 64;
  {
    int tt = threadIdx.x >> 4, ss = threadIdx.x & 15;
    bc[tt][ss] = b2f(dblp[(r0 + tt) * 64 + 32 + ss]);
  }
  const float* Alog = dir ? A_log_b : A_log_f;
  const ushort* dp = delta_bf + dir * USLAB;
  const ushort* up = ucv_bf + dir * USLAB;
  float Ar[D_STATE];
#pragma unroll
  for (int s = 0; s < D_STATE; ++s) Ar[s] = -__expf(Alog[d * D_STATE + s]);
  const bool fast = a_is_arange(Ar);
  float h[D_STATE] = {0.f};
  float dtsum = 0.f;
  __syncthreads();

  if (fast) {
    for (int t = 0; t < CL; ++t) {
      long r = r0 + t;
      float dt = b2f(dp[r * 1024 + d]);
      float u  = b2f(up[r * 1024 + d]);
      float du = dt * u;
      dtsum += dt;
      float Ep[16];
      EP_FAST(dt, Ep);
#pragma unroll
      for (int s = 0; s < D_STATE; ++s)
        h[s] = fmaf(h[s], Ep[s], du * bc[t][s]);
    }
  } else {
    for (int t = 0; t < CL; ++t) {
      long r = r0 + t;
      float dt = b2f(dp[r * 1024 + d]);
      float u  = b2f(up[r * 1024 + d]);
      float du = dt * u;
      dtsum += dt;
#pragma unroll
      for (int s = 0; s < D_STATE; ++s)
        h[s] = fmaf(h[s], __expf(dt * Ar[s]), du * bc[t][s]);
    }
  }
  long base = ((long)((dir * 8 + b) * CH + c) * D_STATE) * 1024 + d;
#pragma unroll
  for (int s = 0; s < D_STATE; ++s) hend[base + s * 1024] = f2b(h[s]);
  dtsum_buf[(long)((dir * 8 + b) * CH + c) * 1024 + d] = dtsum;
}

__global__ __launch_bounds__(256) void scan_partB(
    ushort* __restrict__ hend,
    const float* __restrict__ dtsum_buf,
    const float* __restrict__ A_log_f, const float* __restrict__ A_log_b)
{
  long idx = (long)blockIdx.x * 256 + threadIdx.x;
  int d = (int)idx & 1023;
  int s = ((int)idx >> 10) & 15;
  int b = ((int)idx >> 14) & 7;
  int dir = (int)(idx >> 17);
  const float* Alog = dir ? A_log_b : A_log_f;
  float Ars = -__expf(Alog[d * D_STATE + s]);
  float H = 0.f;
  for (int c = 0; c < CH; ++c) {
    long off = ((long)((dir * 8 + b) * CH + c) * D_STATE + s) * 1024 + d;
    float he = b2f(hend[off]);
    float P = __expf(Ars * dtsum_buf[(long)((dir * 8 + b) * CH + c) * 1024 + d]);
    hend[off] = f2b(H);
    H = fmaf(P, H, he);
  }
}

__global__ __launch_bounds__(256) void scan_partC(
    const ushort* __restrict__ delta_bf,
    const ushort* __restrict__ ucv_bf,
    const ushort* __restrict__ dblb,
    const float* __restrict__ A_log_f, const float* __restrict__ A_log_b,
    const float* __restrict__ Dp_f, const float* __restrict__ Dp_b,
    const ushort* __restrict__ zsilu_bf,
    const ushort* __restrict__ hinit,
    ushort* __restrict__ ydz_bf)
{
  __shared__ float bc[CL][32];
  long idx = (long)blockIdx.x * 256 + threadIdx.x;
  int d = (int)idx & 1023;
  int c = ((int)idx >> 10) & (CH - 1);
  int b = ((int)idx >> 16) & 7;
  int dir = (int)(idx >> 19);
  const long r0 = (long)b * SEQ + c * CL;
  const ushort* dblp = dblb + (long)dir * NROWS * 64;
  {
    int tt = threadIdx.x >> 4, cc = (threadIdx.x & 15) * 2;
    ushort2 v = *(const ushort2*)&dblp[(r0 + tt) * 64 + 32 + cc];
    bc[tt][cc] = b2f(v.x); bc[tt][cc + 1] = b2f(v.y);
  }
  const float* Alog = dir ? A_log_b : A_log_f;
  const ushort* dp = delta_bf + dir * USLAB;
  const ushort* up = ucv_bf + dir * USLAB;
  const ushort* zp = zsilu_bf + dir * USLAB;
  ushort* yp = ydz_bf + dir * USLAB;
  float Ar[D_STATE];
#pragma unroll
  for (int s = 0; s < D_STATE; ++s) Ar[s] = -__expf(Alog[d * D_STATE + s]);
  const bool fast = a_is_arange(Ar);
  float h[D_STATE];
  long base = ((long)((dir * 8 + b) * CH + c) * D_STATE) * 1024 + d;
#pragma unroll
  for (int s = 0; s < D_STATE; ++s) h[s] = b2f(hinit[base + s * 1024]);
  float Dd = (dir ? Dp_b : Dp_f)[d];
  __syncthreads();

  if (fast) {
    for (int t = 0; t < CL; ++t) {
      long r = r0 + t;
      float dt = b2f(dp[r * 1024 + d]);
      float u  = b2f(up[r * 1024 + d]);
      float du = dt * u;
      float Ep[16];
      EP_FAST(dt, Ep);
      float y = 0.f;
#pragma unroll
      for (int s = 0; s < D_STATE; ++s) {
        h[s] = fmaf(h[s], Ep[s], du * bc[t][s]);
        y = fmaf(h[s], bc[t][16 + s], y);
      }
      float zs = b2f(zp[r * 1024 + d]);
      float yv = fmaf(u, Dd, y);
      yp[r * 1024 + d] = f2b(yv * zs);
    }
  } else {
    for (int t = 0; t < CL; ++t) {
      long r = r0 + t;
      float dt = b2f(dp[r * 1024 + d]);
      float u  = b2f(up[r * 1024 + d]);
      float du = dt * u;
      float y = 0.f;
#pragma unroll
      for (int s = 0; s < D_STATE; ++s) {
        h[s] = fmaf(h[s], __expf(dt * Ar[s]), du * bc[t][s]);
        y = fmaf(h[s], bc[t][16 + s], y);
      }
      float zs = b2f(zp[r * 1024 + d]);
      float yv = fmaf(u, Dd, y);
      yp[r * 1024 + d] = f2b(yv * zs);
    }
  }
}

extern "C" void kernel_launch(void* const* d_in, const int* in_sizes, int n_in,
                              void* d_out, int out_size, void* d_ws, size_t ws_size,
                              hipStream_t stream)
{
  const float* x = (const float*)d_in[0];
  float* out = (float*)d_out;
  char* ws = (char*)d_ws;
  ushort* zsilu  = (ushort*)(ws);                     // 32 MiB
  ushort* ucv    = (ushort*)(ws + (32ul << 20));      // 32 MiB (=ydz)
  ushort* u_bf   = (ushort*)(ws + (64ul << 20));      // 32 MiB (=delta)
  ushort* hend   = (ushort*)(ws + (96ul << 20));      // 32 MiB
  float*  dtsum  = (float*)(ws + (128ul << 20));      //  4 MiB
  ushort* dblb   = (ushort*)(ws + (132ul << 20));     //  2 MiB
  ushort* out_wb = (ushort*)(ws + (134ul << 20));     //  2 MiB
  ushort* xbf    = hend;                              // transient in hend slab
  ushort* in_wb  = hend + (8ul << 19);
  ushort* xp_wb  = hend + (12ul << 19);
  ushort* dt_wb  = xp_wb + 131072;
  ushort* delta  = u_bf;
  ushort* ydz    = ucv;

  ConvArgs ca;
  int bcur = 0, si = 0;
  auto addseg = [&](const float* s, ushort* d, int nelem) {
    ca.seg[si].s = (const float4*)s; ca.seg[si].d = (ushort4*)d;
    ca.seg[si].n4 = nelem / 4; ca.seg[si].bstart = bcur;
    bcur += (nelem / 4 + 255) / 256; ++si;
  };
  addseg(x, xbf, NROWS * D_MODEL);
  addseg((const float*)d_in[1], in_wb, 2048 * 512);
  addseg((const float*)d_in[10], in_wb + 2048 * 512, 2048 * 512);
  addseg((const float*)d_in[9], out_wb, 512 * 1024);
  addseg((const float*)d_in[18], out_wb + 512 * 1024, 512 * 1024);
  addseg((const float*)d_in[4], xp_wb, 64 * 1024);
  addseg((const float*)d_in[13], xp_wb + 65536, 64 * 1024);
  addseg((const float*)d_in[5], dt_wb, 1024 * 32);
  addseg((const float*)d_in[14], dt_wb + 32768, 1024 * 32);

  dim3 blk(256);
  convert_all<<<dim3(bcur), blk, 0, stream>>>(ca);

  // 1) merged in_proj via template (128x128, 48 KB LDS -> 3 blocks/CU)
  gemm_bf16<128, 128, 2, 2, 2, 0, 0><<<dim3(32, 64), blk, 0, stream>>>(
      xbf, D_MODEL, nullptr, in_wb, D_MODEL, nullptr,
      nullptr, u_bf, zsilu, 0, D_MODEL, nullptr, nullptr, 0, 0, 0);
  // 2) conv + silu, both dirs
  conv_silu<<<dim3(2 * NROWS), blk, 0, stream>>>(
      u_bf, (const float*)d_in[2], (const float*)d_in[11],
      (const float*)d_in[3], (const float*)d_in[12], ucv);
  // 3) x_proj, both dirs block-diag
  gemm_bf16<64, 64, 2, 2, 4, 0, 1><<<dim3(1, 256), blk, 0, stream>>>(
      ucv, D_INNER, nullptr, xp_wb, D_INNER, nullptr,
      nullptr, dblb, nullptr, 64, D_INNER, nullptr, nullptr, 65536, 0, 0);
  // 4) dt_proj + softplus, both dirs block-diag (pad-80 vectorized epilogue)
  gemm_bf16<128, 128, 2, 2, 1, 0, 1><<<dim3(8, 128), blk, 0, stream>>>(
      dblb, 64, nullptr, dt_wb, DT_RANK, nullptr,
      nullptr, delta, nullptr, D_INNER, DT_RANK,
      (const float*)d_in[6], (const float*)d_in[15], 32768, 0, 0);
  // 5) chunked scan, both dirs
  const float* Alf = (const float*)d_in[7];
  const float* Alb = (const float*)d_in[16];
  scan_partA<<<dim3(2 * BATCH * CH * 1024 / 256), blk, 0, stream>>>(
      delta, ucv, dblb, Alf, Alb, hend, dtsum);
  scan_partB<<<dim3(2 * BATCH * 16 * 1024 / 256), blk, 0, stream>>>(
      hend, dtsum, Alf, Alb);
  scan_partC<<<dim3(2 * BATCH * CH * 1024 / 256), blk, 0, stream>>>(
      delta, ucv, dblb, Alf, Alb,
      (const float*)d_in[8], (const float*)d_in[17], zsilu, hend, ydz);
  // 6) out_proj, both dirs in one K=2048 dispatch
  gemm_bf16<128, 128, 2, 2, 0, 1, 0><<<dim3(4, 64), blk, 0, stream>>>(
      ydz, D_INNER, ydz + USLAB, out_wb, D_INNER, out_wb + 512 * 1024,
      out, nullptr, nullptr, D_MODEL, 2 * D_INNER, nullptr, nullptr, 0, 0, 0);
}

// Round 20
// 235.475 us; speedup vs baseline: 1.0211x; 1.0211x over previous
//
#include <hip/hip_runtime.h>
#include <math.h>

#define BATCH 8
#define SEQ 1024
#define D_MODEL 512
#define D_INNER 1024
#define D_STATE 16
#define DT_RANK 32
#define NROWS (BATCH * SEQ)   // 8192
#define CH 64                 // chunks per sequence
#define CL 16                 // chunk length
#define USLAB 8388608l        // 8192*1024 elems (one dir slab)

typedef short short8 __attribute__((ext_vector_type(8)));
typedef float f32x4 __attribute__((ext_vector_type(4)));

__device__ __forceinline__ float sigmoidf_(float x) { return 1.f / (1.f + __expf(-x)); }

__device__ __forceinline__ float softplus_(float v) {
  return (v > 20.f) ? v : __logf(1.f + __expf(v));
}

__device__ __forceinline__ ushort f2b(float f) {  // fp32 -> bf16 RNE
  uint u = __float_as_uint(f);
  return (ushort)((u + 0x7FFFu + ((u >> 16) & 1u)) >> 16);
}
__device__ __forceinline__ float b2f(ushort u) {
  return __uint_as_float(((uint)u) << 16);
}

__device__ __forceinline__ void gload16(const ushort* g, const ushort* l) {
  __builtin_amdgcn_global_load_lds(
      (const __attribute__((address_space(1))) void*)g,
      (__attribute__((address_space(3))) void*)l, 16, 0, 0);
}

__device__ __forceinline__ int revrow(int m) {
  return (m & ~1023) | (1023 - (m & 1023));
}

#define VMCNT0 asm volatile("s_waitcnt vmcnt(0)" ::: "memory")
#define VMCNT2 asm volatile("s_waitcnt vmcnt(2)" ::: "memory")
#define VMCNT3 asm volatile("s_waitcnt vmcnt(3)" ::: "memory")
#define VMCNT4 asm volatile("s_waitcnt vmcnt(4)" ::: "memory")

// scr stride 68: concurrent epilogue-write rows are spaced 4 apart;
// 4*68 ushorts = 136 dwords == 8 mod 32 -> rows at bank offsets {0,8,16,24},
// 16 lanes/row span 8 dword-banks -> 32 banks total, write conflict-free.
#define SCR_LD 68

// ========== in_proj: 256x128 tile, 8 waves, counted-vmcnt, 2 blocks/CU =====
__global__ __launch_bounds__(512, 4) void inproj256(
    const ushort* __restrict__ A, int lda,      // [8192][512]
    const ushort* __restrict__ B, int ldb,      // [4096][512]
    ushort* __restrict__ Cu, ushort* __restrict__ Cz,
    int K)
{
  __shared__ ushort As[3][256 * 32];            // 48 KB
  __shared__ ushort Bs[3][128 * 32];            // 24 KB
  const int tid = threadIdx.x;
  const int w = tid >> 6, lane = tid & 63;

  const int nwg = gridDim.x * gridDim.y;        // 1024, %8 == 0
  int bid = blockIdx.y * gridDim.x + blockIdx.x;
  int wgid = (bid & 7) * (nwg >> 3) + (bid >> 3);
  const int bm = (wgid / gridDim.x) * 256;
  const int bn = (wgid % gridDim.x) * 128;

  const int wr = w >> 1, wc = w & 1;            // 4x2 wave grid
  const int rw0 = wr * 64, cw0 = wc * 64;
  const int srow = w * 16 + (lane >> 2);
  const int scol = (((lane & 3) ^ ((lane >> 3) & 3)) << 3);
  const int rchunk = (((lane >> 4) ^ (((lane & 15) >> 1) & 3)) << 3);

  f32x4 acc[4][4] = {};

  auto stage = [&](int buf, int k0) {
#pragma unroll
    for (int half = 0; half < 2; ++half) {
      int gm = bm + half * 128 + srow;
      gload16(A + (long)gm * lda + k0 + scol, &As[buf][(half * 128 + w * 16) * 32]);
    }
    int gn = bn + srow;
    gload16(B + (long)gn * ldb + k0 + scol, &Bs[buf][(w * 16) * 32]);
  };

  const int NT = K >> 5;
  stage(0, 0);
  stage(1, 32);
  VMCNT3;
  __builtin_amdgcn_s_barrier();

  int buf = 0;
  for (int t = 0; t < NT; ++t) {
    short8 a[4], b[4];
#pragma unroll
    for (int i = 0; i < 4; ++i)
      a[i] = *(const short8*)&As[buf][(rw0 + i * 16 + (lane & 15)) * 32 + rchunk];
#pragma unroll
    for (int j = 0; j < 4; ++j)
      b[j] = *(const short8*)&Bs[buf][(cw0 + j * 16 + (lane & 15)) * 32 + rchunk];
    int sbuf = (buf >= 1) ? buf - 1 : buf + 2;
    if (t + 2 < NT) {
      stage(sbuf, (t + 2) << 5);
      VMCNT3;
    } else if (t + 1 < NT) {
      VMCNT0;
    }
    __builtin_amdgcn_s_barrier();
    __builtin_amdgcn_s_setprio(1);
#pragma unroll
    for (int i = 0; i < 4; ++i)
#pragma unroll
      for (int j = 0; j < 4; ++j)
        acc[i][j] = __builtin_amdgcn_mfma_f32_16x16x32_bf16(a[i], b[j], acc[i][j], 0, 0, 0);
    __builtin_amdgcn_s_setprio(0);
    buf = (buf == 2) ? 0 : buf + 1;
  }
  __builtin_amdgcn_s_barrier();

  const int bdir = bn >> 11;
  const int bz = ((bn & 2047) >= 1024);
  const int bncol = bn & 1023;
  ushort* Cp = (bz ? Cz : Cu) + (long)bdir * USLAB;
  ushort* scr = &As[0][0] + w * (16 * SCR_LD);

#pragma unroll
  for (int i = 0; i < 4; ++i) {
#pragma unroll
    for (int r = 0; r < 4; ++r)
#pragma unroll
      for (int j = 0; j < 4; ++j) {
        float v = acc[i][j][r];
        if (bz) v = v * sigmoidf_(v);
        scr[((lane >> 4) * 4 + r) * SCR_LD + j * 16 + (lane & 15)] = f2b(v);
      }
#pragma unroll
    for (int q = 0; q < 2; ++q) {
      int r16 = (lane >> 3) + q * 8;
      short8 pk = *(const short8*)&scr[r16 * SCR_LD + (lane & 7) * 8];
      int m = bm + rw0 + i * 16 + r16;
      int row = bdir ? revrow(m) : m;
      *(short8*)&Cp[(long)row * 1024 + bncol + cw0 + (lane & 7) * 8] = pk;
    }
  }
}

// -------- bf16 MFMA GEMM: 3-buffer counted-vmcnt, single barrier/K-tile ----
// EPI: 0 = fp32 store (revC/accumC), 1 = softplus->bf16 (LDS-transposed),
//      4 = plain bf16
template<int BM, int BN, int RW, int CW, int EPI, int DUALK, int MDIAG>
__global__ __launch_bounds__(256) void gemm_bf16(
    const ushort* __restrict__ A, int lda, const ushort* __restrict__ A2,
    const ushort* __restrict__ B, int ldb, const ushort* __restrict__ B2,
    float* __restrict__ Cf, ushort* __restrict__ Cb,
    int ldc, int K, const float* __restrict__ bias, const float* __restrict__ bias2,
    int b_stride, int revC, int accumC)
{
  constexpr int MI = BM / RW / 16;
  constexpr int NJ = BN / CW / 16;
  constexpr int LPS = BM / 64 + BN / 64;   // loads per stage per thread
  __shared__ ushort As[3][BM * 32];
  __shared__ ushort Bs[3][BN * 32];
  const int tid = threadIdx.x;
  const int w = tid >> 6, lane = tid & 63;

  const int nwg = gridDim.x * gridDim.y;
  int bid = blockIdx.y * gridDim.x + blockIdx.x;
  int wgid = (bid & 7) * (nwg >> 3) + (bid >> 3);
  const int bm = (wgid / gridDim.x) * BM;
  const int bn = (wgid % gridDim.x) * BN;

  if (MDIAG) {
    int mdir = (bm >= NROWS) ? 1 : 0;
    B += mdir * b_stride;
    if (mdir) bias = bias2;
  }

  const int rw0 = (w / CW) * (MI * 16);
  const int cw0 = (w % CW) * (NJ * 16);
  const int srow = w * 16 + (lane >> 2);
  const int scol = (((lane & 3) ^ ((lane >> 3) & 3)) << 3);
  const int rchunk = (((lane >> 4) ^ (((lane & 15) >> 1) & 3)) << 3);

  f32x4 acc[MI][NJ] = {};

  auto stage = [&](int buf, int k0) {
    const ushort* Ap = A;
    const ushort* Bp = B;
    int kc = k0;
    bool hi = false;
    if (DUALK && k0 >= (K >> 1)) { Ap = A2; Bp = B2; kc = k0 - (K >> 1); hi = true; }
#pragma unroll
    for (int it = 0; it < BM / 64; ++it) {
      int gm = bm + it * 64 + srow;
      int arow = (DUALK && hi) ? revrow(gm) : gm;
      gload16(Ap + (long)arow * lda + kc + scol, &As[buf][(it * 64 + w * 16) * 32]);
    }
#pragma unroll
    for (int it = 0; it < BN / 64; ++it) {
      int gn = bn + it * 64 + srow;
      gload16(Bp + (long)gn * ldb + kc + scol, &Bs[buf][(it * 64 + w * 16) * 32]);
    }
  };

  const int NT = K >> 5;
  stage(0, 0);
  if (NT > 1) {
    stage(1, 32);
    if constexpr (LPS == 2) VMCNT2; else VMCNT4;
  } else {
    VMCNT0;
  }
  __builtin_amdgcn_s_barrier();

  int buf = 0;
  for (int t = 0; t < NT; ++t) {
    short8 a[MI], b[NJ];
#pragma unroll
    for (int i = 0; i < MI; ++i)
      a[i] = *(const short8*)&As[buf][(rw0 + i * 16 + (lane & 15)) * 32 + rchunk];
#pragma unroll
    for (int j = 0; j < NJ; ++j)
      b[j] = *(const short8*)&Bs[buf][(cw0 + j * 16 + (lane & 15)) * 32 + rchunk];
    int sbuf = (buf >= 1) ? buf - 1 : buf + 2;
    if (t + 2 < NT) {
      stage(sbuf, (t + 2) << 5);
      if constexpr (LPS == 2) VMCNT2; else VMCNT4;
    } else if (t + 1 < NT) {
      VMCNT0;
    }
    __builtin_amdgcn_s_barrier();
    __builtin_amdgcn_s_setprio(1);
#pragma unroll
    for (int i = 0; i < MI; ++i)
#pragma unroll
      for (int j = 0; j < NJ; ++j)
        acc[i][j] = __builtin_amdgcn_mfma_f32_16x16x32_bf16(a[i], b[j], acc[i][j], 0, 0, 0);
    __builtin_amdgcn_s_setprio(0);
    buf = (buf == 2) ? 0 : buf + 1;
  }
  __builtin_amdgcn_s_barrier();

  if (EPI == 1) {
    ushort* scr = &As[0][0] + w * (16 * SCR_LD);
#pragma unroll
    for (int i = 0; i < MI; ++i) {
#pragma unroll
      for (int r = 0; r < 4; ++r)
#pragma unroll
        for (int j = 0; j < NJ; ++j) {
          int n = bn + cw0 + j * 16 + (lane & 15);
          float v = softplus_(acc[i][j][r] + bias[n]);
          scr[((lane >> 4) * 4 + r) * SCR_LD + j * 16 + (lane & 15)] = f2b(v);
        }
#pragma unroll
      for (int q = 0; q < 2; ++q) {
        int r16 = (lane >> 3) + q * 8;
        short8 pk = *(const short8*)&scr[r16 * SCR_LD + (lane & 7) * 8];
        int m = bm + rw0 + i * 16 + r16;
        *(short8*)&Cb[(long)m * ldc + bn + cw0 + (lane & 7) * 8] = pk;
      }
    }
  } else {
#pragma unroll
    for (int i = 0; i < MI; ++i)
#pragma unroll
      for (int r = 0; r < 4; ++r) {
        int m = bm + rw0 + i * 16 + (lane >> 4) * 4 + r;
        int crow = revC ? revrow(m) : m;
#pragma unroll
        for (int j = 0; j < NJ; ++j) {
          int n = bn + cw0 + j * 16 + (lane & 15);
          float v = acc[i][j][r];
          if (EPI == 0) {
            float* p = Cf + (long)crow * ldc + n;
            if (accumC) *p += v; else *p = v;
          } else {  // EPI == 4
            Cb[(long)crow * ldc + n] = f2b(v);
          }
        }
      }
  }
}

// ---------------- fused fp32->bf16 converter (x + 8 weight tensors) --------
struct Seg { const float4* s; ushort4* d; int n4; int bstart; };
struct ConvArgs { Seg seg[9]; };

__global__ __launch_bounds__(256) void convert_all(ConvArgs a)
{
  int blk = blockIdx.x;
  int i = 0;
#pragma unroll
  for (int k = 1; k < 9; ++k) if (blk >= a.seg[k].bstart) i = k;
  int idx = (blk - a.seg[i].bstart) * 256 + threadIdx.x;
  if (idx >= a.seg[i].n4) return;
  float4 v = a.seg[i].s[idx];
  ushort4 o;
  o.x = f2b(v.x); o.y = f2b(v.y); o.z = f2b(v.z); o.w = f2b(v.w);
  a.seg[i].d[idx] = o;
}

// ------------- conv1d(k=4) + bias + silu, both dirs (4 d/thread) -----------
__global__ __launch_bounds__(256) void conv_silu(
    const ushort* __restrict__ u_bf,
    const float* __restrict__ cw_f, const float* __restrict__ cw_b,
    const float* __restrict__ cb_f, const float* __restrict__ cb_b,
    ushort* __restrict__ uc_bf)
{
  long i = (long)blockIdx.x * 256 + threadIdx.x;
  int dir = (int)(i >> 21);
  int r = (int)(i >> 8) & 8191;
  int d0 = ((int)i & 255) << 2;
  int t = r & (SEQ - 1);
  const float* cw = dir ? cw_b : cw_f;
  const float* cb = dir ? cb_b : cb_f;
  const ushort* p = u_bf + dir * USLAB + (long)r * D_INNER + d0;
  ushort4 u0 = *(const ushort4*)p;
  ushort4 u1 = (t >= 1) ? *(const ushort4*)(p - 1024) : ushort4{0, 0, 0, 0};
  ushort4 u2 = (t >= 2) ? *(const ushort4*)(p - 2048) : ushort4{0, 0, 0, 0};
  ushort4 u3 = (t >= 3) ? *(const ushort4*)(p - 3072) : ushort4{0, 0, 0, 0};
  float4 bb = *(const float4*)(cb + d0);
  float ub0[4] = {b2f(u0.x), b2f(u0.y), b2f(u0.z), b2f(u0.w)};
  float ub1[4] = {b2f(u1.x), b2f(u1.y), b2f(u1.z), b2f(u1.w)};
  float ub2[4] = {b2f(u2.x), b2f(u2.y), b2f(u2.z), b2f(u2.w)};
  float ub3[4] = {b2f(u3.x), b2f(u3.y), b2f(u3.z), b2f(u3.w)};
  float bbv[4] = {bb.x, bb.y, bb.z, bb.w};
  ushort ov[4];
#pragma unroll
  for (int j = 0; j < 4; ++j) {
    float4 wj = *(const float4*)(cw + (d0 + j) * 4);
    float acc = bbv[j];
    acc = fmaf(wj.w, ub0[j], acc);
    acc = fmaf(wj.z, ub1[j], acc);
    acc = fmaf(wj.y, ub2[j], acc);
    acc = fmaf(wj.x, ub3[j], acc);
    ov[j] = f2b(acc * sigmoidf_(acc));
  }
  ushort4 o;
  o.x = ov[0]; o.y = ov[1]; o.z = ov[2]; o.w = ov[3];
  *(ushort4*)(uc_bf + dir * USLAB + (long)r * D_INNER + d0) = o;
}

// Decay powers E^(s+1), s=0..15, from E = exp(-dt).
#define EP_FAST(dt, Ep)                                        \
  {                                                            \
    float E1 = __expf(-(dt));                                  \
    float E2 = E1 * E1, E4 = E2 * E2, E8 = E4 * E4;            \
    Ep[0] = E1;  Ep[1] = E2;      Ep[2] = E2 * E1;             \
    Ep[3] = E4;  Ep[4] = E4 * E1; Ep[5] = E4 * E2;             \
    Ep[6] = E4 * Ep[2]; Ep[7] = E8;  Ep[8] = E8 * E1;          \
    Ep[9] = E8 * E2; Ep[10] = E8 * Ep[2]; Ep[11] = E8 * E4;    \
    Ep[12] = E8 * Ep[4]; Ep[13] = E8 * Ep[5];                  \
    Ep[14] = E8 * Ep[6]; Ep[15] = E8 * E8;                     \
  }

__device__ __forceinline__ bool a_is_arange(const float* Ar) {
  bool ok = true;
#pragma unroll
  for (int s = 0; s < D_STATE; ++s)
    ok = ok && (fabsf(Ar[s] + (float)(s + 1)) <= 1e-3f * (float)(s + 1));
  return ok;
}

// ---------------- chunked selective scan (both dirs in one grid) -----------
__global__ __launch_bounds__(256) void scan_partA(
    const ushort* __restrict__ delta_bf,
    const ushort* __restrict__ ucv_bf,
    const ushort* __restrict__ dblb,
    const float* __restrict__ A_log_f, const float* __restrict__ A_log_b,
    ushort* __restrict__ hend,
    float* __restrict__ dtsum_buf)
{
  __shared__ float bc[CL][16];
  long idx = (long)blockIdx.x * 256 + threadIdx.x;
  int d = (int)idx & 1023;
  int c = ((int)idx >> 10) & (CH - 1);
  int b = ((int)idx >> 16) & 7;
  int dir = (int)(idx >> 19);
  const long r0 = (long)b * SEQ + c * CL;
  const ushort* dblp = dblb + (long)dir * NROWS * 64;
  {
    int tt = threadIdx.x >> 4, ss = threadIdx.x & 15;
    bc[tt][ss] = b2f(dblp[(r0 + tt) * 64 + 32 + ss]);
  }
  const float* Alog = dir ? A_log_b : A_log_f;
  const ushort* dp = delta_bf + dir * USLAB;
  const ushort* up = ucv_bf + dir * USLAB;
  float Ar[D_STATE];
#pragma unroll
  for (int s = 0; s < D_STATE; ++s) Ar[s] = -__expf(Alog[d * D_STATE + s]);
  const bool fast = a_is_arange(Ar);
  float h[D_STATE] = {0.f};
  float dtsum = 0.f;
  __syncthreads();

  if (fast) {
    for (int t = 0; t < CL; ++t) {
      long r = r0 + t;
      float dt = b2f(dp[r * 1024 + d]);
      float u  = b2f(up[r * 1024 + d]);
      float du = dt * u;
      dtsum += dt;
      float Ep[16];
      EP_FAST(dt, Ep);
#pragma unroll
      for (int s = 0; s < D_STATE; ++s)
        h[s] = fmaf(h[s], Ep[s], du * bc[t][s]);
    }
  } else {
    for (int t = 0; t < CL; ++t) {
      long r = r0 + t;
      float dt = b2f(dp[r * 1024 + d]);
      float u  = b2f(up[r * 1024 + d]);
      float du = dt * u;
      dtsum += dt;
#pragma unroll
      for (int s = 0; s < D_STATE; ++s)
        h[s] = fmaf(h[s], __expf(dt * Ar[s]), du * bc[t][s]);
    }
  }
  long base = ((long)((dir * 8 + b) * CH + c) * D_STATE) * 1024 + d;
#pragma unroll
  for (int s = 0; s < D_STATE; ++s) hend[base + s * 1024] = f2b(h[s]);
  dtsum_buf[(long)((dir * 8 + b) * CH + c) * 1024 + d] = dtsum;
}

__global__ __launch_bounds__(256) void scan_partB(
    ushort* __restrict__ hend,
    const float* __restrict__ dtsum_buf,
    const float* __restrict__ A_log_f, const float* __restrict__ A_log_b)
{
  long idx = (long)blockIdx.x * 256 + threadIdx.x;
  int d = (int)idx & 1023;
  int s = ((int)idx >> 10) & 15;
  int b = ((int)idx >> 14) & 7;
  int dir = (int)(idx >> 17);
  const float* Alog = dir ? A_log_b : A_log_f;
  float Ars = -__expf(Alog[d * D_STATE + s]);
  float H = 0.f;
  for (int c = 0; c < CH; ++c) {
    long off = ((long)((dir * 8 + b) * CH + c) * D_STATE + s) * 1024 + d;
    float he = b2f(hend[off]);
    float P = __expf(Ars * dtsum_buf[(long)((dir * 8 + b) * CH + c) * 1024 + d]);
    hend[off] = f2b(H);
    H = fmaf(P, H, he);
  }
}

__global__ __launch_bounds__(256) void scan_partC(
    const ushort* __restrict__ delta_bf,
    const ushort* __restrict__ ucv_bf,
    const ushort* __restrict__ dblb,
    const float* __restrict__ A_log_f, const float* __restrict__ A_log_b,
    const float* __restrict__ Dp_f, const float* __restrict__ Dp_b,
    const ushort* __restrict__ zsilu_bf,
    const ushort* __restrict__ hinit,
    ushort* __restrict__ ydz_bf)
{
  __shared__ float bc[CL][32];
  long idx = (long)blockIdx.x * 256 + threadIdx.x;
  int d = (int)idx & 1023;
  int c = ((int)idx >> 10) & (CH - 1);
  int b = ((int)idx >> 16) & 7;
  int dir = (int)(idx >> 19);
  const long r0 = (long)b * SEQ + c * CL;
  const ushort* dblp = dblb + (long)dir * NROWS * 64;
  {
    int tt = threadIdx.x >> 4, cc = (threadIdx.x & 15) * 2;
    ushort2 v = *(const ushort2*)&dblp[(r0 + tt) * 64 + 32 + cc];
    bc[tt][cc] = b2f(v.x); bc[tt][cc + 1] = b2f(v.y);
  }
  const float* Alog = dir ? A_log_b : A_log_f;
  const ushort* dp = delta_bf + dir * USLAB;
  const ushort* up = ucv_bf + dir * USLAB;
  const ushort* zp = zsilu_bf + dir * USLAB;
  ushort* yp = ydz_bf + dir * USLAB;
  float Ar[D_STATE];
#pragma unroll
  for (int s = 0; s < D_STATE; ++s) Ar[s] = -__expf(Alog[d * D_STATE + s]);
  const bool fast = a_is_arange(Ar);
  float h[D_STATE];
  long base = ((long)((dir * 8 + b) * CH + c) * D_STATE) * 1024 + d;
#pragma unroll
  for (int s = 0; s < D_STATE; ++s) h[s] = b2f(hinit[base + s * 1024]);
  float Dd = (dir ? Dp_b : Dp_f)[d];
  __syncthreads();

  if (fast) {
    for (int t = 0; t < CL; ++t) {
      long r = r0 + t;
      float dt = b2f(dp[r * 1024 + d]);
      float u  = b2f(up[r * 1024 + d]);
      float du = dt * u;
      float Ep[16];
      EP_FAST(dt, Ep);
      float y = 0.f;
#pragma unroll
      for (int s = 0; s < D_STATE; ++s) {
        h[s] = fmaf(h[s], Ep[s], du * bc[t][s]);
        y = fmaf(h[s], bc[t][16 + s], y);
      }
      float zs = b2f(zp[r * 1024 + d]);
      float yv = fmaf(u, Dd, y);
      yp[r * 1024 + d] = f2b(yv * zs);
    }
  } else {
    for (int t = 0; t < CL; ++t) {
      long r = r0 + t;
      float dt = b2f(dp[r * 1024 + d]);
      float u  = b2f(up[r * 1024 + d]);
      float du = dt * u;
      float y = 0.f;
#pragma unroll
      for (int s = 0; s < D_STATE; ++s) {
        h[s] = fmaf(h[s], __expf(dt * Ar[s]), du * bc[t][s]);
        y = fmaf(h[s], bc[t][16 + s], y);
      }
      float zs = b2f(zp[r * 1024 + d]);
      float yv = fmaf(u, Dd, y);
      yp[r * 1024 + d] = f2b(yv * zs);
    }
  }
}

extern "C" void kernel_launch(void* const* d_in, const int* in_sizes, int n_in,
                              void* d_out, int out_size, void* d_ws, size_t ws_size,
                              hipStream_t stream)
{
  const float* x = (const float*)d_in[0];
  float* out = (float*)d_out;
  char* ws = (char*)d_ws;
  ushort* zsilu  = (ushort*)(ws);                     // 32 MiB
  ushort* ucv    = (ushort*)(ws + (32ul << 20));      // 32 MiB (=ydz)
  ushort* u_bf   = (ushort*)(ws + (64ul << 20));      // 32 MiB (=delta)
  ushort* hend   = (ushort*)(ws + (96ul << 20));      // 32 MiB
  float*  dtsum  = (float*)(ws + (128ul << 20));      //  4 MiB
  ushort* dblb   = (ushort*)(ws + (132ul << 20));     //  2 MiB
  ushort* out_wb = (ushort*)(ws + (134ul << 20));     //  2 MiB
  ushort* xbf    = hend;                              // transient in hend slab
  ushort* in_wb  = hend + (8ul << 19);
  ushort* xp_wb  = hend + (12ul << 19);
  ushort* dt_wb  = xp_wb + 131072;
  ushort* delta  = u_bf;
  ushort* ydz    = ucv;

  ConvArgs ca;
  int bcur = 0, si = 0;
  auto addseg = [&](const float* s, ushort* d, int nelem) {
    ca.seg[si].s = (const float4*)s; ca.seg[si].d = (ushort4*)d;
    ca.seg[si].n4 = nelem / 4; ca.seg[si].bstart = bcur;
    bcur += (nelem / 4 + 255) / 256; ++si;
  };
  addseg(x, xbf, NROWS * D_MODEL);
  addseg((const float*)d_in[1], in_wb, 2048 * 512);
  addseg((const float*)d_in[10], in_wb + 2048 * 512, 2048 * 512);
  addseg((const float*)d_in[9], out_wb, 512 * 1024);
  addseg((const float*)d_in[18], out_wb + 512 * 1024, 512 * 1024);
  addseg((const float*)d_in[4], xp_wb, 64 * 1024);
  addseg((const float*)d_in[13], xp_wb + 65536, 64 * 1024);
  addseg((const float*)d_in[5], dt_wb, 1024 * 32);
  addseg((const float*)d_in[14], dt_wb + 32768, 1024 * 32);

  dim3 blk(256);
  convert_all<<<dim3(bcur), blk, 0, stream>>>(ca);

  // 1) merged in_proj: 256x128 tiles, 2 blocks/CU (R18-proven shape)
  inproj256<<<dim3(4096 / 128, NROWS / 256), dim3(512), 0, stream>>>(
      xbf, D_MODEL, in_wb, D_MODEL, u_bf, zsilu, D_MODEL);
  // 2) conv + silu, both dirs
  conv_silu<<<dim3(2 * NROWS), blk, 0, stream>>>(
      u_bf, (const float*)d_in[2], (const float*)d_in[11],
      (const float*)d_in[3], (const float*)d_in[12], ucv);
  // 3) x_proj, both dirs block-diag
  gemm_bf16<64, 64, 2, 2, 4, 0, 1><<<dim3(1, 256), blk, 0, stream>>>(
      ucv, D_INNER, nullptr, xp_wb, D_INNER, nullptr,
      nullptr, dblb, 64, D_INNER, nullptr, nullptr, 65536, 0, 0);
  // 4) dt_proj + softplus, both dirs block-diag (pad-68 vectorized epilogue)
  gemm_bf16<128, 128, 2, 2, 1, 0, 1><<<dim3(8, 128), blk, 0, stream>>>(
      dblb, 64, nullptr, dt_wb, DT_RANK, nullptr,
      nullptr, delta, D_INNER, DT_RANK,
      (const float*)d_in[6], (const float*)d_in[15], 32768, 0, 0);
  // 5) chunked scan, both dirs
  const float* Alf = (const float*)d_in[7];
  const float* Alb = (const float*)d_in[16];
  scan_partA<<<dim3(2 * BATCH * CH * 1024 / 256), blk, 0, stream>>>(
      delta, ucv, dblb, Alf, Alb, hend, dtsum);
  scan_partB<<<dim3(2 * BATCH * 16 * 1024 / 256), blk, 0, stream>>>(
      hend, dtsum, Alf, Alb);
  scan_partC<<<dim3(2 * BATCH * CH * 1024 / 256), blk, 0, stream>>>(
      delta, ucv, dblb, Alf, Alb,
      (const float*)d_in[8], (const float*)d_in[17], zsilu, hend, ydz);
  // 6) out_proj, both dirs in one K=2048 dispatch
  gemm_bf16<128, 128, 2, 2, 0, 1, 0><<<dim3(4, 64), blk, 0, stream>>>(
      ydz, D_INNER, ydz + USLAB, out_wb, D_INNER, out_wb + 512 * 1024,
      out, nullptr, D_MODEL, 2 * D_INNER, nullptr, nullptr, 0, 0, 0);
}